// Round 1
// 1549.004 us; speedup vs baseline: 1.3743x; 1.3743x over previous
//
#include <hip/hip_runtime.h>
#include <hip/hip_bf16.h>

// CustomLSTMModel: emb(32000x300 fp32, pad_idx=0) -> LSTM(300->512, 512 steps, B=256, fp32)
//                  -> FC(512->7, fp32). tokens int32; out fp32 [256,7].
// Internal: bf16 MFMA (RNE), fp32 accum/c/biases/FC. absmax ~1e-3 (R2/R4/R5: 9.8e-4).
//
// R7 changes vs R6 (2128 us; on-CU critical path was LDS BW: 416 ds_read_b128/CU/step
// ~ 5000cy at ~12cy/b128 > 2000cy MFMA, and only 128/256 CUs in use):
//  - Re-decompose: 16 groups x 16 batches (N=16, one MFMA N-tile), 16 blocks/group x
//    32 units, 256 blocks x 256 threads (4 waves). Each wave holds TWO 16-row M-tiles
//    of A in VGPRs (~208 regs) and reads each B-fragment ONCE, feeding both M-tiles:
//    per-CU b128 reads 416 -> 104, MFMA 416 -> 208, across all 256 CUs.
//  - Sync protocol unchanged: flags now [256] (16 per group), group = bid&15 keeps a
//    group's 16 blocks on one XCD (bid==g mod 16 => same bid mod 8).
// Carried from R6/R5/R4: x_{t+1} emb software prefetch into VGPRs; no fences (relaxed
// agent-scope atomics, LLC-coherent); coalesced u64 h writeback via LDS bounce; W in
// VGPRs; c in VGPRs; wave-0-only poll; 0xAAAAAAAA poison < 1 monotonic flags.

typedef unsigned short ushort_t;
typedef unsigned long long u64_t;
typedef __bf16 bf16x8 __attribute__((ext_vector_type(8)));
typedef unsigned short u16x8v __attribute__((ext_vector_type(8)));
typedef float f32x4 __attribute__((ext_vector_type(4)));

#define U_STRIDE 840   // ushorts: 320 (x incl zero pad) + 512 (h) + 8 pad; row = 1680B
#define HOFF 320
#define SCR_S 36       // scratch row stride in ushorts (72B)

__device__ __forceinline__ float sigmoidf_(float x) { return 1.0f / (1.0f + __expf(-x)); }
__device__ __forceinline__ float tanhf_(float x)    { return 1.0f - 2.0f / (__expf(2.0f * x) + 1.0f); }

__device__ __forceinline__ ushort_t f2bf(float f) {   // RNE; inputs finite
    unsigned u = __builtin_bit_cast(unsigned, f);
    unsigned r = (u + 0x7FFFu + ((u >> 16) & 1u)) >> 16;
    return (ushort_t)r;
}
__device__ __forceinline__ float bf2f(ushort_t u) {
    unsigned v = ((unsigned)u) << 16;
    return __builtin_bit_cast(float, v);
}

// LLC-coherent (cache-bypassing) accessors — relaxed agent atomics, no fences.
__device__ __forceinline__ u64_t g_load64(const u64_t* p) {
    return __hip_atomic_load(p, __ATOMIC_RELAXED, __HIP_MEMORY_SCOPE_AGENT);
}
__device__ __forceinline__ void g_store64(u64_t* p, u64_t v) {
    __hip_atomic_store(p, v, __ATOMIC_RELAXED, __HIP_MEMORY_SCOPE_AGENT);
}
__device__ __forceinline__ int g_load_flag(const int* p) {
    return __hip_atomic_load(p, __ATOMIC_RELAXED, __HIP_MEMORY_SCOPE_AGENT);
}
__device__ __forceinline__ void g_store_flag(int* p, int v) {
    __hip_atomic_store(p, v, __ATOMIC_RELAXED, __HIP_MEMORY_SCOPE_AGENT);
}

__global__ __launch_bounds__(256, 1)
void lstm_fused_kernel(const int* __restrict__ tokens,    // [256][512]
                       const float* __restrict__ emb,     // [32000][300]
                       const float* __restrict__ Wih,     // [2048][300]
                       const float* __restrict__ bih,     // [2048]
                       const float* __restrict__ Whh,     // [2048][512]
                       const float* __restrict__ bhh,     // [2048]
                       const float* __restrict__ Wfc,     // [7][512]
                       const float* __restrict__ bfc,     // [7]
                       float* __restrict__ out,           // [256][7]
                       int* __restrict__ flags,           // [256]
                       ushort_t* __restrict__ hbuf)       // [2][256][512] bf16
{
    __shared__ ushort_t u_lds[16 * U_STRIDE];   // 26880 B (16 batch rows)
    __shared__ ushort_t h_scr[16 * SCR_S];      // 1152 B writeback bounce

    const int tid = threadIdx.x;
    const int bid = blockIdx.x;
    const int g   = bid & 15;      // batch group 0..15 (16 batches; blocks share an XCD)
    const int ib  = bid >> 4;      // block-in-group 0..15 -> unit slice
    const int Bg0 = g * 16;
    const int U0  = ib * 32;       // 32 units per block
    const int lane = tid & 63;
    const int wv   = tid >> 6;     // wave 0..3; wave owns 2 M-tiles (32 gate rows)
    const int lm   = lane & 15;
    const int q    = lane >> 4;

    // ---- preload A-fragments for BOTH M-tiles, fp32 -> bf16 RNE (once) ----
    // M-tile m of wave wv = block gate rows [32*wv + 16*m, +16). rp = unit_local*4+gate.
    bf16x8 aih[2][10];
    bf16x8 ahh[2][16];
#pragma unroll
    for (int m = 0; m < 2; ++m) {
        const int rp   = 32 * wv + 16 * m + lm;
        const int gi   = rp & 3;
        const int up   = rp >> 2;               // unit_local 0..31
        const int grow = gi * 512 + U0 + up;    // global gate row (i,f,g,o blocks of 512)
#pragma unroll
        for (int kc = 0; kc < 10; ++kc) {
            u16x8v tmp;
#pragma unroll
            for (int j = 0; j < 8; ++j) {
                int col = 32 * kc + 8 * q + j;
                tmp[j] = (col < 300) ? f2bf(Wih[grow * 300 + col]) : (ushort_t)0;
            }
            aih[m][kc] = __builtin_bit_cast(bf16x8, tmp);
        }
#pragma unroll
        for (int kc = 0; kc < 16; ++kc) {
            u16x8v tmp;
#pragma unroll
            for (int j = 0; j < 8; ++j) {
                int col = 32 * kc + 8 * q + j;
                tmp[j] = f2bf(Whh[grow * 512 + col]);
            }
            ahh[m][kc] = __builtin_bit_cast(bf16x8, tmp);
        }
    }

    // ---- per-lane biases (fp32): M-tile m output unit = U0 + 8*wv + 4*m + q ----
    float bias[2][4];
#pragma unroll
    for (int m = 0; m < 2; ++m) {
        const int unit = U0 + 8 * wv + 4 * m + q;
#pragma unroll
        for (int j = 0; j < 4; ++j)
            bias[m][j] = bih[j * 512 + unit] + bhh[j * 512 + unit];
    }

    // ---- init: zero our unit-slice of h parity-0 (h0=0) via bypassing stores ----
    if (tid < 128) {
        int r = tid >> 3;        // batch row 0..15
        int d = tid & 7;         // 8 u64 = 32 units
        g_store64((u64_t*)(hbuf + (size_t)(Bg0 + r) * 512 + U0 + 4 * d), 0ull);
    }
    __syncthreads();             // drains stores before barrier
    if (tid == 0) g_store_flag(&flags[g * 16 + ib], 1);

    const int* myflag = &flags[g * 16 + (lane & 15)];
    float c0 = 0.0f, c1 = 0.0f;

    // ---- x prefetch state: thread handles row xr = tid>>4, elements xln+16k ----
    const int xr  = tid >> 4;        // batch row 0..15
    const int xln = tid & 15;
    const int xb  = Bg0 + xr;
    int tok_cur = tokens[xb * 512 + 0];
    int tok_nxt = tokens[xb * 512 + 1];
    float2 xp[10];
    {
        const float2* s2 = (const float2*)(emb + (size_t)tok_cur * 300);
#pragma unroll
        for (int k = 0; k < 10; ++k) {
            int i = xln + 16 * k;
            if (i < 150) xp[k] = s2[i];
        }
    }

    for (int t = 0; t < 512; ++t) {
        // ---- consume prefetched x_t: fp32 -> bf16 pairs -> LDS ----
        {
            unsigned int* dstx = (unsigned int*)(u_lds + xr * U_STRIDE);
            const bool tz = (tok_cur != 0);
#pragma unroll
            for (int k = 0; k < 10; ++k) {     // 160 dwords: 150 data + 10 zero pad
                int i = xln + 16 * k;
                unsigned int v = 0u;
                if (tz && i < 150)
                    v = (unsigned int)f2bf(xp[k].x) | ((unsigned int)f2bf(xp[k].y) << 16);
                dstx[i] = v;
            }
        }
        // ---- issue prefetch for x_{t+1} (overlaps the whole step body) ----
        {
            tok_cur = tok_nxt;
            const float2* s2 = (const float2*)(emb + (size_t)tok_cur * 300);
#pragma unroll
            for (int k = 0; k < 10; ++k) {
                int i = xln + 16 * k;
                if (i < 150) xp[k] = s2[i];
            }
            int t2 = (t + 2 < 512) ? (t + 2) : 511;
            tok_nxt = tokens[xb * 512 + t2];
        }
        __syncthreads();   // S1: x staged

        // ---- ih-MFMAs (h-independent): one B read feeds both M-tiles ----
        f32x4 acc0 = {0.f, 0.f, 0.f, 0.f};
        f32x4 acc1 = {0.f, 0.f, 0.f, 0.f};
        const ushort_t* u0 = u_lds + lm * U_STRIDE + 8 * q;   // batches Bg0+0..15
#pragma unroll
        for (int kc = 0; kc < 10; ++kc) {
            bf16x8 b0 = __builtin_bit_cast(bf16x8, *(const u16x8v*)(u0 + 32 * kc));
            acc0 = __builtin_amdgcn_mfma_f32_16x16x32_bf16(aih[0][kc], b0, acc0, 0, 0, 0);
            acc1 = __builtin_amdgcn_mfma_f32_16x16x32_bf16(aih[1][kc], b0, acc1, 0, 0, 0);
        }

        // ---- wave 0 polls peers' flags (monotonic; 0xAAAAAAAA poison < 1) ----
        if (wv == 0) {
            const int target = t + 1;
            while (true) {
                int v = g_load_flag(myflag);
                if (__all(v >= target)) break;
                __builtin_amdgcn_s_sleep(1);
            }
            asm volatile("" ::: "memory");   // no reordering of h loads above the poll
        }
        __syncthreads();   // S2a: release all waves

        // ---- stage h_t via bypassing u64 loads -> LDS (128 u64 = 1 KB per row) ----
        {
            const int r  = tid >> 4;       // batch row 0..15
            const int ln = tid & 15;
            const u64_t* hsrc = (const u64_t*)(hbuf + (size_t)(t & 1) * (256 * 512)
                                               + (size_t)(Bg0 + r) * 512);
            u64_t* dsth = (u64_t*)(u_lds + r * U_STRIDE + HOFF);
            u64_t tmp[8];
#pragma unroll
            for (int k = 0; k < 8; ++k) tmp[k] = g_load64(hsrc + ln + 16 * k);
#pragma unroll
            for (int k = 0; k < 8; ++k) dsth[ln + 16 * k] = tmp[k];
        }
        __syncthreads();   // S2b: h staged

        // ---- hh-MFMAs: one B read feeds both M-tiles ----
#pragma unroll
        for (int kc = 0; kc < 16; ++kc) {
            bf16x8 b0 = __builtin_bit_cast(bf16x8, *(const u16x8v*)(u0 + HOFF + 32 * kc));
            acc0 = __builtin_amdgcn_mfma_f32_16x16x32_bf16(ahh[0][kc], b0, acc0, 0, 0, 0);
            acc1 = __builtin_amdgcn_mfma_f32_16x16x32_bf16(ahh[1][kc], b0, acc1, 0, 0, 0);
        }

        // ---- elementwise LSTM (lane-local: acc_m = i,f,g,o of unit 8wv+4m+q) ----
        {
            {
                float ig = sigmoidf_(acc0.x + bias[0][0]);
                float fg = sigmoidf_(acc0.y + bias[0][1]);
                float gg = tanhf_(acc0.z + bias[0][2]);
                float og = sigmoidf_(acc0.w + bias[0][3]);
                c0 = fg * c0 + ig * gg;
                h_scr[lm * SCR_S + 8 * wv + q] = f2bf(og * tanhf_(c0));
            }
            {
                float ig = sigmoidf_(acc1.x + bias[1][0]);
                float fg = sigmoidf_(acc1.y + bias[1][1]);
                float gg = tanhf_(acc1.z + bias[1][2]);
                float og = sigmoidf_(acc1.w + bias[1][3]);
                c1 = fg * c1 + ig * gg;
                h_scr[lm * SCR_S + 8 * wv + 4 + q] = f2bf(og * tanhf_(c1));
            }
        }
        __syncthreads();   // S3a: scratch complete (lgkmcnt drain)

        // ---- coalesced bypassing writeback: 128 x u64 (64B-contiguous per row) ----
        if (tid < 128) {
            const int r = tid >> 3;    // batch row 0..15
            const int d = tid & 7;     // u64 index 0..7 (4 units each)
            u64_t v = *(const u64_t*)((const char*)h_scr + r * (SCR_S * 2) + d * 8);
            ushort_t* hdst = hbuf + (size_t)((t + 1) & 1) * (256 * 512);
            g_store64((u64_t*)(hdst + (size_t)(Bg0 + r) * 512 + U0 + 4 * d), v);
        }
        __syncthreads();   // S3b: vmcnt(0) drain -> h stores at LLC before publish
        if (tid == 0) g_store_flag(&flags[g * 16 + ib], t + 2);
    }

    // ---- wait group done (513), then FC: block handles batch Bg0+ib ----
    if (wv == 0) {
        while (true) {
            int v = g_load_flag(myflag);
            if (__all(v >= 513)) break;
            __builtin_amdgcn_s_sleep(1);
        }
        asm volatile("" ::: "memory");
    }
    __syncthreads();

    {
        const int bb = Bg0 + ib;
        const ushort_t* hrow = hbuf + (size_t)bb * 512;  // final h in parity 0
        u64_t h0 = g_load64((const u64_t*)(hrow + lane * 8));
        u64_t h1 = g_load64((const u64_t*)(hrow + lane * 8 + 4));
        float hv[8];
#pragma unroll
        for (int j = 0; j < 4; ++j) hv[j]     = bf2f((ushort_t)(h0 >> (16 * j)));
#pragma unroll
        for (int j = 0; j < 4; ++j) hv[4 + j] = bf2f((ushort_t)(h1 >> (16 * j)));
#pragma unroll
        for (int oo = 0; oo < 2; ++oo) {
            int o = wv + 4 * oo;       // waves 0..3 -> o {0,4},{1,5},{2,6},{3}
            if (o < 7) {
                f32x4 w0 = *(const f32x4*)(Wfc + o * 512 + lane * 8);
                f32x4 w1 = *(const f32x4*)(Wfc + o * 512 + lane * 8 + 4);
                float s = hv[0] * w0.x + hv[1] * w0.y + hv[2] * w0.z + hv[3] * w0.w
                        + hv[4] * w1.x + hv[5] * w1.y + hv[6] * w1.z + hv[7] * w1.w;
#pragma unroll
                for (int sh = 32; sh >= 1; sh >>= 1) s += __shfl_down(s, sh);
                if (lane == 0)
                    out[bb * 7 + o] = s + bfc[o];
            }
        }
    }
}

extern "C" void kernel_launch(void* const* d_in, const int* in_sizes, int n_in,
                              void* d_out, int out_size, void* d_ws, size_t ws_size,
                              hipStream_t stream) {
    const int* tokens = (const int*)d_in[0];
    const float* emb  = (const float*)d_in[1];
    const float* Wih  = (const float*)d_in[2];
    const float* bih  = (const float*)d_in[3];
    const float* Whh  = (const float*)d_in[4];
    const float* bhh  = (const float*)d_in[5];
    const float* Wfc  = (const float*)d_in[6];
    const float* bfc  = (const float*)d_in[7];

    int* flags      = (int*)d_ws;                       // 256 ints (group g: flags[16g..16g+15])
    ushort_t* hbuf  = (ushort_t*)((char*)d_ws + 1024);  // [2][256][512] bf16 = 512 KiB

    lstm_fused_kernel<<<dim3(256), dim3(256), 0, stream>>>(
        tokens, emb, Wih, bih, Whh, bhh, Wfc, bfc,
        (float*)d_out, flags, hbuf);
}